// Round 1
// baseline (294.696 us; speedup 1.0000x reference)
//
#include <hip/hip_runtime.h>

#define NHEAD 8
#define HDIM 32
#define SUMP 16
#define NQ 300
#define NBS 32
#define VTOT 8500
#define CDIM 256
#define TQ 16
#define NQT 19  // ceil(300/16)

__global__ __launch_bounds__(256, 8)
void msda_kernel(const float* __restrict__ query,
                 const float* __restrict__ refp,
                 const float* __restrict__ value,
                 const float* __restrict__ W_off,
                 const float* __restrict__ b_off,
                 const float* __restrict__ W_attn,
                 const float* __restrict__ b_attn,
                 float* __restrict__ out) {
    // LDS: query tile (padded stride 260), later aliased by P (corner table)
    __shared__ float Aq[TQ * 260];        // 16640 B
    __shared__ float S[TQ * 49];          // 48 GEMM outputs per q, padded
    __shared__ float Rp[TQ * 4];

    float* P = Aq;  // alias: P[TQ*16*8] = 2048 floats <= 4160 (safe, after barrier)

    const int tid = threadIdx.x;
    const int bh  = blockIdx.x & 255;
    const int b   = bh >> 3;
    const int h   = bh & 7;
    const int qt  = blockIdx.x >> 8;
    const int q0  = qt * TQ;

    // ---- phase 0: stage query tile + reference points ----
    #pragma unroll
    for (int i = 0; i < 4; ++i) {
        int f4 = i * 256 + tid;            // 0..1023 float4 slots
        int q  = f4 >> 6;                  // 16 rows
        int kk = (f4 & 63) << 2;           // float col 0..252
        float4 v = make_float4(0.f, 0.f, 0.f, 0.f);
        if (q0 + q < NQ)
            v = *reinterpret_cast<const float4*>(
                    query + ((size_t)(b * NQ + q0 + q) * CDIM + kk));
        *reinterpret_cast<float4*>(&Aq[q * 260 + kk]) = v;
    }
    if (tid < TQ * 4) {
        int q = tid >> 2, c = tid & 3;
        Rp[tid] = (q0 + q < NQ) ? refp[((size_t)(b * NQ + q0 + q)) * 4 + c] : 0.5f;
    }
    __syncthreads();

    // ---- phase 1: GEMM — 16 q x 48 outputs (32 offset cols + 16 attn logits), K=256 ----
    {
        const int q  = tid >> 4;
        const int oi = tid & 15;
        const float* Wo = W_off  + h * 32;   // this head's 32 offset columns
        const float* Wa = W_attn + h * 16;   // this head's 16 attn columns
        float acc0 = b_off[h * 32 + oi];
        float acc1 = b_off[h * 32 + 16 + oi];
        float acc2 = b_attn[h * 16 + oi];
        const float* a = &Aq[q * 260];
        #pragma unroll 4
        for (int k = 0; k < CDIM; ++k) {
            float av = a[k];
            acc0 = fmaf(av, Wo[k * 256 + oi], acc0);
            acc1 = fmaf(av, Wo[k * 256 + 16 + oi], acc1);
            acc2 = fmaf(av, Wa[k * 128 + oi], acc2);
        }
        S[q * 49 + oi]      = acc0;
        S[q * 49 + 16 + oi] = acc1;
        S[q * 49 + 32 + oi] = acc2;
    }
    __syncthreads();

    // ---- phase 2: per (q,p): softmax weight + location + corner idx/weight precompute ----
    {
        const int q = tid >> 4;
        const int p = tid & 15;
        const float* Sq = &S[q * 49];

        float m = Sq[32];
        #pragma unroll
        for (int j = 1; j < 16; ++j) m = fmaxf(m, Sq[32 + j]);
        float ssum = 0.f;
        #pragma unroll
        for (int j = 0; j < 16; ++j) ssum += __expf(Sq[32 + j] - m);
        float aw = __expf(Sq[32 + p] - m) / ssum;

        float offx = Sq[2 * p], offy = Sq[2 * p + 1];
        float rx = Rp[q * 4 + 0], ry = Rp[q * 4 + 1];
        float rw = Rp[q * 4 + 2], rh = Rp[q * 4 + 3];
        // offset = off * nps(=0.25) * wh * OFFSET_SCALE(=0.5)
        float locx = rx + offx * 0.25f * rw * 0.5f;
        float locy = ry + offy * 0.25f * rh * 0.5f;

        int l  = p >> 2;                   // 4 points per level
        int Wl = 80 >> l;                  // 80,40,20,10 (square levels)
        int Hl = Wl;
        int base = (l > 0 ? 6400 : 0) + (l > 1 ? 1600 : 0) + (l > 2 ? 400 : 0);

        float x = locx * (float)Wl - 0.5f;
        float y = locy * (float)Hl - 0.5f;
        float x0f = floorf(x), y0f = floorf(y);
        float lx = x - x0f, ly = y - y0f;
        int x0 = (int)x0f, y0 = (int)y0f;
        int x1 = x0 + 1,   y1 = y0 + 1;

        bool vx0 = (x0 >= 0) && (x0 < Wl);
        bool vx1 = (x1 >= 0) && (x1 < Wl);
        bool vy0 = (y0 >= 0) && (y0 < Hl);
        bool vy1 = (y1 >= 0) && (y1 < Hl);
        int cx0 = min(max(x0, 0), Wl - 1), cx1 = min(max(x1, 0), Wl - 1);
        int cy0 = min(max(y0, 0), Hl - 1), cy1 = min(max(y1, 0), Hl - 1);

        int i00 = base + cy0 * Wl + cx0;
        int i10 = base + cy0 * Wl + cx1;
        int i01 = base + cy1 * Wl + cx0;
        int i11 = base + cy1 * Wl + cx1;

        float wx0 = 1.f - lx, wy0 = 1.f - ly;
        float w00 = wx0 * wy0 * aw * (float)(vx0 && vy0);
        float w10 = lx  * wy0 * aw * (float)(vx1 && vy0);
        float w01 = wx0 * ly  * aw * (float)(vx0 && vy1);
        float w11 = lx  * ly  * aw * (float)(vx1 && vy1);

        float* Pe = &P[(q * 16 + p) * 8];
        Pe[0] = __int_as_float(i00);
        Pe[1] = __int_as_float(i10);
        Pe[2] = __int_as_float(i01);
        Pe[3] = __int_as_float(i11);
        Pe[4] = w00;
        Pe[5] = w10;
        Pe[6] = w01;
        Pe[7] = w11;
    }
    __syncthreads();

    // ---- phase 3: gather-accumulate. lanes: 32 channels (coalesced 128B per corner) ----
    {
        const int qi = tid >> 5;          // 8 query-slots
        const int ch = tid & 31;
        const float* vptr = value + (size_t)b * VTOT * CDIM + h * 32 + ch;
        for (int qq = qi; qq < TQ; qq += 8) {
            float acc = 0.f;
            #pragma unroll
            for (int p = 0; p < 16; ++p) {
                const float* Pe = &P[(qq * 16 + p) * 8];
                int4   id = *reinterpret_cast<const int4*>(Pe);
                float4 w  = *reinterpret_cast<const float4*>(Pe + 4);
                acc = fmaf(w.x, vptr[(size_t)id.x * CDIM], acc);
                acc = fmaf(w.y, vptr[(size_t)id.y * CDIM], acc);
                acc = fmaf(w.z, vptr[(size_t)id.z * CDIM], acc);
                acc = fmaf(w.w, vptr[(size_t)id.w * CDIM], acc);
            }
            int q = q0 + qq;
            if (q < NQ)
                out[((size_t)b * NQ + q) * CDIM + h * 32 + ch] = acc;
        }
    }
}

extern "C" void kernel_launch(void* const* d_in, const int* in_sizes, int n_in,
                              void* d_out, int out_size, void* d_ws, size_t ws_size,
                              hipStream_t stream) {
    const float* query  = (const float*)d_in[0];
    const float* refp   = (const float*)d_in[1];
    const float* value  = (const float*)d_in[2];
    const float* W_off  = (const float*)d_in[3];
    const float* b_off  = (const float*)d_in[4];
    const float* W_attn = (const float*)d_in[5];
    const float* b_attn = (const float*)d_in[6];
    float* out = (float*)d_out;

    dim3 grid(NQT * 256);   // qt-major so all q-tiles of a (b,h) share an XCD (256 % 8 == 0)
    dim3 block(256);
    hipLaunchKernelGGL(msda_kernel, grid, block, 0, stream,
                       query, refp, value, W_off, b_off, W_attn, b_attn, out);
}